// Round 18
// baseline (220.769 us; speedup 1.0000x reference)
//
#include <hip/hip_runtime.h>
#include <hip/hip_bf16.h>
#include <cmath>

#define NE   2048
#define NH   32
#define NKV  8
#define HD   64
#define SEQ  2048
#define NB   2

typedef __attribute__((ext_vector_type(4))) float f32x4;
typedef __attribute__((ext_vector_type(16))) float f32x16;
typedef __attribute__((ext_vector_type(8))) short bf16x8;
typedef __attribute__((ext_vector_type(4))) short bf16x4;

typedef const __attribute__((address_space(1))) void cgvoid;
typedef __attribute__((address_space(3))) void lvoid;

// SCALE fold: softmax uses exp2; fold (1/8)*log2(e) into Q projection.
#define QSCALE 0.18033688011112042f

__device__ __forceinline__ short f2bf(float f) {
  union { float f; unsigned u; } v; v.f = f;
  unsigned r = v.u + 0x7fffu + ((v.u >> 16) & 1u);
  return (short)(r >> 16);
}

__device__ __forceinline__ unsigned cvt_pk_bf16(float a, float b) {
  unsigned r;
  asm("v_cvt_pk_bf16_f32 %0, %1, %2" : "=v"(r) : "v"(a), "v"(b));
  return r;
}

// ---------------- fused f32 -> bf16 conversion, all 7 tensors, 16 elems/thread ----
__global__ __launch_bounds__(256) void cvt_all(
    const float* __restrict__ s0, short* __restrict__ d0,
    const float* __restrict__ s1, short* __restrict__ d1,
    const float* __restrict__ s2, short* __restrict__ d2,
    const float* __restrict__ s3, short* __restrict__ d3,
    const float* __restrict__ s4, short* __restrict__ d4,
    const float* __restrict__ s5, short* __restrict__ d5,
    const float* __restrict__ s6, short* __restrict__ d6)
{
  int idx = (blockIdx.x * 256 + threadIdx.x) * 2;   // first item index
  const float* s; short* d; int rel;
  if      (idx < 1048576) { s = s0; d = d0; rel = idx; }
  else if (idx < 2097152) { s = s1; d = d1; rel = idx - 1048576; }
  else if (idx < 3145728) { s = s2; d = d2; rel = idx - 2097152; }
  else if (idx < 3670016) { s = s3; d = d3; rel = idx - 3145728; }
  else if (idx < 3801088) { s = s4; d = d4; rel = idx - 3670016; }
  else if (idx < 3932160) { s = s5; d = d5; rel = idx - 3801088; }
  else                    { s = s6; d = d6; rel = idx - 3932160; }
  size_t off = (size_t)rel * 8;
  f32x4 a0 = *(const f32x4*)(s + off);
  f32x4 b0 = *(const f32x4*)(s + off + 4);
  f32x4 a1 = *(const f32x4*)(s + off + 8);
  f32x4 b1 = *(const f32x4*)(s + off + 12);
  bf16x8 o0, o1;
  #pragma unroll
  for (int j = 0; j < 4; ++j) {
    o0[j] = f2bf(a0[j]); o0[4 + j] = f2bf(b0[j]);
    o1[j] = f2bf(a1[j]); o1[4 + j] = f2bf(b1[j]);
  }
  *(bf16x8*)(d + off) = o0;
  *(bf16x8*)(d + off + 8) = o1;
}

// ================= 256x256 8-wave QKV-projection GEMM (R12 bf16 body) =============
template<int EPI>
__device__ __forceinline__ void gemm256_body(
    short* As, short* Ws, int m0, int n0,
    const short* __restrict__ A, const short* __restrict__ W,
    const float* __restrict__ bias, void* __restrict__ Cout, int K)
{
  const int t = threadIdx.x, lane = t & 63, w = t >> 6;
  const int lr = lane & 15, lg = lane >> 4;
  const int wm = (w >> 2) * 128, wn = (w & 3) * 64;

  f32x4 acc[8][4];
  #pragma unroll
  for (int i = 0; i < 8; ++i)
    #pragma unroll
    for (int j = 0; j < 4; ++j) acc[i][j] = (f32x4){0.f, 0.f, 0.f, 0.f};

  auto STAGE = [&](int kt) {
    const int k0 = kt << 6;
    short* Ad = As + (kt & 1) * 16384;
    short* Wd = Ws + (kt & 1) * 16384;
    #pragma unroll
    for (int it = 0; it < 4; ++it) {
      int e = it * 512 + t, r = e >> 3, c = e & 7;
      int cs = ((c ^ (r & 7)) << 3);
      __builtin_amdgcn_global_load_lds((cgvoid*)(A + (size_t)(m0 + r) * K + k0 + cs),
                                       (lvoid*)(Ad + e * 8), 16, 0, 0);
      __builtin_amdgcn_global_load_lds((cgvoid*)(W + (size_t)(n0 + r) * K + k0 + cs),
                                       (lvoid*)(Wd + e * 8), 16, 0, 0);
    }
  };

  const int nt = K >> 6;  // 32
  STAGE(0);

  #pragma unroll 1
  for (int ti = 0; ti < nt; ++ti) {
    const short* Ab = As + (ti & 1) * 16384;
    const short* Wb = Ws + (ti & 1) * 16384;
    if (ti + 1 < nt) {
      STAGE(ti + 1);
      asm volatile("s_waitcnt vmcnt(8)" ::: "memory");
    } else {
      asm volatile("s_waitcnt vmcnt(0)" ::: "memory");
    }
    __builtin_amdgcn_s_barrier();

    bf16x8 wf[2][4];
    #pragma unroll
    for (int ks = 0; ks < 2; ++ks)
      #pragma unroll
      for (int nf = 0; nf < 4; ++nf) {
        int row = wn + nf * 16 + lr;
        wf[ks][nf] = *(const bf16x8*)(Wb + row * 64 + (((ks * 4 + lg) ^ (row & 7)) << 3));
      }
    #pragma unroll
    for (int mq = 0; mq < 4; ++mq) {
      bf16x8 af[2][2];
      #pragma unroll
      for (int ks = 0; ks < 2; ++ks)
        #pragma unroll
        for (int mi = 0; mi < 2; ++mi) {
          int row = wm + (mq * 2 + mi) * 16 + lr;
          af[ks][mi] = *(const bf16x8*)(Ab + row * 64 + (((ks * 4 + lg) ^ (row & 7)) << 3));
        }
      __builtin_amdgcn_s_setprio(1);
      #pragma unroll
      for (int ks = 0; ks < 2; ++ks)
        #pragma unroll
        for (int mi = 0; mi < 2; ++mi)
          #pragma unroll
          for (int nf = 0; nf < 4; ++nf)
            acc[mq * 2 + mi][nf] =
                __builtin_amdgcn_mfma_f32_16x16x32_bf16(af[ks][mi], wf[ks][nf],
                                                        acc[mq * 2 + mi][nf], 0, 0, 0);
      __builtin_amdgcn_s_setprio(0);
    }
    __builtin_amdgcn_s_barrier();
  }

  if (EPI == 1) {
    short* C = (short*)Cout;
    #pragma unroll
    for (int mf = 0; mf < 8; ++mf)
      #pragma unroll
      for (int nf = 0; nf < 4; ++nf) {
        int n = n0 + wn + nf * 16 + lr;
        int kv = n >> 6, d = n & 63;
        int mb = m0 + wm + mf * 16 + lg * 4;
        int b = mb >> 11, s = mb & (SEQ - 1);
        bf16x4 pb;
        #pragma unroll
        for (int i = 0; i < 4; ++i) pb[i] = f2bf(acc[mf][nf][i] + bias[n]);
        *(bf16x4*)(C + (((size_t)b * NKV + kv) * HD + d) * SEQ + s) = pb;
      }
  } else {
    const int HN = (EPI == 2) ? NH : NKV;
    short* C = (short*)Cout;
    #pragma unroll
    for (int mf = 0; mf < 8; ++mf)
      #pragma unroll
      for (int nf2 = 0; nf2 < 2; ++nf2) {
        int n1 = n0 + wn + nf2 * 16 + lr;
        int d1 = n1 & 63;  // < 32
        int h = n1 >> 6;
        float inv = exp2f(-(float)d1 * (13.287712379549449f / 32.0f));
        #pragma unroll
        for (int i = 0; i < 4; ++i) {
          int m = m0 + wm + mf * 16 + lg * 4 + i;
          int b = m >> 11, s = m & (SEQ - 1);
          float v1 = acc[mf][nf2][i] + bias[n1];
          float v2 = acc[mf][nf2 + 2][i] + bias[n1 + 32];
          float ang = (float)s * inv;
          float c, sn;
          __sincosf(ang, &sn, &c);
          float o1 = v1 * c - v2 * sn;
          float o2 = v2 * c + v1 * sn;
          if (EPI == 2) { o1 *= QSCALE; o2 *= QSCALE; }
          size_t base = (((size_t)b * HN + h) * SEQ + s) * HD;
          C[base + d1]      = f2bf(o1);
          C[base + d1 + 32] = f2bf(o2);
        }
      }
  }
}

// Block->XCD mapping: all 12 blocks sharing one A-panel land on XCD (mm&7).
__global__ __launch_bounds__(512, 2) void gemm_qkv256(
    const short* __restrict__ qA, const short* __restrict__ Wq,
    const float* __restrict__ bq, short* __restrict__ Qout,
    const short* __restrict__ kA, const short* __restrict__ Wk,
    const float* __restrict__ bk, short* __restrict__ Kout,
    const short* __restrict__ vA, const short* __restrict__ Wv,
    const float* __restrict__ bv, short* __restrict__ Vout)
{
  __shared__ __align__(16) short As[2 * 256 * 64];
  __shared__ __align__(16) short Ws[2 * 256 * 64];
  int orig = blockIdx.x;
  int xcd = orig & 7, idx = orig >> 3;
  int hiP = (idx >= 12) ? 1 : 0;
  int mm = xcd + 8 * hiP;
  int j = idx - 12 * hiP;
  if (j < 8) {
    gemm256_body<2>(As, Ws, mm * 256, j * 256, qA, Wq, bq, (void*)Qout, NE);
  } else if (j < 10) {
    gemm256_body<3>(As, Ws, mm * 256, (j - 8) * 256, kA, Wk, bk, (void*)Kout, NE);
  } else {
    gemm256_body<1>(As, Ws, mm * 256, (j - 10) * 256, vA, Wv, bv, (void*)Vout, NE);
  }
}

// ================= O-projection: 128x128 BK=64 dbuf, phase-pinned (R11) =========
__global__ __launch_bounds__(256) void gemm_o(
    const short* __restrict__ A, const short* __restrict__ W,
    const float* __restrict__ bias, float* __restrict__ C, int N, int K)
{
  __shared__ __align__(16) short As[2 * 128 * 64];
  __shared__ __align__(16) short Ws[2 * 128 * 64];
  const int t = threadIdx.x, lane = t & 63, w = t >> 6;
  const int lr = lane & 15, lg = lane >> 4;
  const int wm = (w >> 1) * 64, wn = (w & 1) * 64;
  const int L = blockIdx.x;
  const int xcd = L & 7, slot = L >> 3;
  const int bx = xcd + 8 * (slot >> 4);
  const int byy = slot & 15;
  const int m0 = bx * 128, n0 = byy * 128;

  f32x4 acc[4][4];
  #pragma unroll
  for (int i = 0; i < 4; ++i)
    #pragma unroll
    for (int j = 0; j < 4; ++j) acc[i][j] = (f32x4){0.f, 0.f, 0.f, 0.f};

  const int nt = K >> 6;
  #pragma unroll
  for (int it = 0; it < 4; ++it) {
    int e = it * 256 + t, r = e >> 3, c = e & 7;
    int cs = ((c ^ (r & 7)) << 3);
    __builtin_amdgcn_global_load_lds((cgvoid*)(A + (size_t)(m0 + r) * K + cs),
                                     (lvoid*)(As + e * 8), 16, 0, 0);
    __builtin_amdgcn_global_load_lds((cgvoid*)(W + (size_t)(n0 + r) * K + cs),
                                     (lvoid*)(Ws + e * 8), 16, 0, 0);
  }

  for (int ti = 0; ti < nt; ++ti) {
    const int cur = ti & 1;
    const short* Ab = As + cur * 8192;
    const short* Wb = Ws + cur * 8192;
    if (ti + 1 < nt) {
      const int k0 = (ti + 1) << 6;
      short* An = As + (cur ^ 1) * 8192;
      short* Wn = Ws + (cur ^ 1) * 8192;
      #pragma unroll
      for (int it = 0; it < 4; ++it) {
        int e = it * 256 + t, r = e >> 3, c = e & 7;
        int cs = ((c ^ (r & 7)) << 3);
        __builtin_amdgcn_global_load_lds((cgvoid*)(A + (size_t)(m0 + r) * K + k0 + cs),
                                         (lvoid*)(An + e * 8), 16, 0, 0);
        __builtin_amdgcn_global_load_lds((cgvoid*)(W + (size_t)(n0 + r) * K + k0 + cs),
                                         (lvoid*)(Wn + e * 8), 16, 0, 0);
      }
      asm volatile("s_waitcnt vmcnt(8)" ::: "memory");
    } else {
      asm volatile("s_waitcnt vmcnt(0)" ::: "memory");
    }
    __builtin_amdgcn_s_barrier();
    __builtin_amdgcn_sched_barrier(0);

    bf16x8 wf[2][4];
    #pragma unroll
    for (int ks = 0; ks < 2; ++ks)
      #pragma unroll
      for (int nf = 0; nf < 4; ++nf) {
        int row = wn + nf * 16 + lr;
        wf[ks][nf] = *(const bf16x8*)(Wb + row * 64 + (((ks * 4 + lg) ^ (row & 7)) << 3));
      }
    #pragma unroll
    for (int mq = 0; mq < 2; ++mq) {
      bf16x8 af[2][2];
      #pragma unroll
      for (int ks = 0; ks < 2; ++ks)
        #pragma unroll
        for (int mi = 0; mi < 2; ++mi) {
          int row = wm + (mq * 2 + mi) * 16 + lr;
          af[ks][mi] = *(const bf16x8*)(Ab + row * 64 + (((ks * 4 + lg) ^ (row & 7)) << 3));
        }
      __builtin_amdgcn_s_setprio(1);
      #pragma unroll
      for (int ks = 0; ks < 2; ++ks)
        #pragma unroll
        for (int mi = 0; mi < 2; ++mi)
          #pragma unroll
          for (int nf = 0; nf < 4; ++nf)
            acc[mq * 2 + mi][nf] =
                __builtin_amdgcn_mfma_f32_16x16x32_bf16(af[ks][mi], wf[ks][nf],
                                                        acc[mq * 2 + mi][nf], 0, 0, 0);
      __builtin_amdgcn_s_setprio(0);
      __builtin_amdgcn_s_barrier();
      __builtin_amdgcn_sched_barrier(0);
    }
  }

  #pragma unroll
  for (int mf = 0; mf < 4; ++mf)
    #pragma unroll
    for (int nf = 0; nf < 4; ++nf)
      #pragma unroll
      for (int i = 0; i < 4; ++i) {
        int m = m0 + wm + mf * 16 + lg * 4 + i;
        int n = n0 + wn + nf * 16 + lr;
        C[(size_t)m * N + n] = acc[mf][nf][i] + bias[n];
      }
}

// ---------------- Flash attention, causal, GQA-shared KV, 32x32 MFMA, KVBLK=128 ----
// 1-D grid 512. XCD-group swizzle (KV-group pinned to one XCD). Block 256 =
// 4 waves = 4 query heads over the same 32 q rows; paired Q-tiles {63-bx, bx}.
// KV tile 128 double-buffered (64 KB LDS): K [128][64], V as 2 halves [64][64]
// (same proven conflict-free swizzle). 32 MFMA per barrier pair.
__global__ __launch_bounds__(256) void attn_kernel(
    const short* __restrict__ Q, const short* __restrict__ K,
    const short* __restrict__ Vt, short* __restrict__ O)
{
  __shared__ __align__(16) short Ks[2][128 * 64];
  __shared__ __align__(16) short Vs[2][2][64 * 64];

  const int t = threadIdx.x, lane = t & 63, w = t >> 6;
  const int l31 = lane & 31, hi = lane >> 5;
  const int L = blockIdx.x;
  const int xcd = L & 7, slot = L >> 3;
  const int by = xcd + 8 * (slot >> 5);
  const int bx = slot & 31;
  const int b = by >> 3, kvh = by & 7;
  const int h = kvh * 4 + w;

  const short* Qh = Q + ((size_t)b * NH + h) * SEQ * HD;
  const short* Kh = K + ((size_t)b * NKV + kvh) * SEQ * HD;
  const short* Vh = Vt + ((size_t)b * NKV + kvh) * (size_t)HD * SEQ;

  #pragma unroll 1
  for (int pass = 0; pass < 2; ++pass) {
    const int qb32 = pass ? bx : (63 - bx);
    const int q0 = qb32 * 32;
    const int ntile = (qb32 >> 2) + 1;   // 128-wide KV tiles
    const int qpos = q0 + l31;

    bf16x8 qfr[4];
    #pragma unroll
    for (int dd = 0; dd < 4; ++dd)
      qfr[dd] = *(const bf16x8*)(Qh + (size_t)(q0 + l31) * HD + dd * 16 + hi * 8);

    f32x16 o[2];
    #pragma unroll
    for (int dh = 0; dh < 2; ++dh)
      #pragma unroll
      for (int r = 0; r < 16; ++r) o[dh][r] = 0.f;
    float lsum = 0.f;

    // stage K/V tile kt into buffer bf (K: 128 rows x 8 chunks; V: 2 halves of
    // 64 rows x 8 chunks). Linear LDS dest + pre-swizzled global source.
    auto STAGE = [&](int kt, int bf) {
      const int kv0 = kt * 128;
      #pragma unroll
      for (int it = 0; it < 4; ++it) {
        int cid = it * 256 + t;
        int r = cid >> 3, c = cid & 7;
        int cs = ((c ^ (r & 7)) << 3);
        __builtin_amdgcn_global_load_lds((cgvoid*)(Kh + (size_t)(kv0 + r) * HD + cs),
                                         (lvoid*)(Ks[bf] + cid * 8), 16, 0, 0);
      }
      #pragma unroll
      for (int hh = 0; hh < 2; ++hh)
        #pragma unroll
        for (int it = 0; it < 2; ++it) {
          int cid = it * 256 + t;
          int r = cid >> 3, c = cid & 7;
          int cs = ((c ^ (r & 7)) << 3);
          __builtin_amdgcn_global_load_lds((cgvoid*)(Vh + (size_t)r * SEQ + kv0 + hh * 64 + cs),
                                           (lvoid*)(Vs[bf][hh] + cid * 8), 16, 0, 0);
        }
    };

    STAGE(0, 0);
    __syncthreads();

    for (int ti = 0; ti < ntile; ++ti) {
      const int cur = ti & 1;
      if (ti + 1 < ntile) STAGE(ti + 1, cur ^ 1);
      const int kv0 = ti * 128;
      const short* Kb = Ks[cur];
      const bool diag = (ti == ntile - 1);

      unsigned pa[8][4];
      #pragma unroll
      for (int f = 0; f < 4; ++f) {
        f32x16 z;
        #pragma unroll
        for (int r = 0; r < 16; ++r) z[r] = 0.f;
        __builtin_amdgcn_s_setprio(1);
        #pragma unroll
        for (int dd = 0; dd < 4; ++dd) {
          int row = f * 32 + l31;
          bf16x8 ka = *(const bf16x8*)(Kb + row * 64 + (((2 * dd + hi) ^ (row & 7)) << 3));
          z = __builtin_amdgcn_mfma_f32_32x32x16_bf16(ka, qfr[dd], z, 0, 0, 0);
        }
        __builtin_amdgcn_s_setprio(0);
        if (diag) {
          #pragma unroll
          for (int r = 0; r < 16; ++r) {
            int kpos = kv0 + f * 32 + (r & 3) + 8 * (r >> 2) + 4 * hi;
            if (kpos > qpos) z[r] = -INFINITY;
          }
        }
        float e[16];
        #pragma unroll
        for (int r = 0; r < 16; ++r) {
          e[r] = __builtin_amdgcn_exp2f(z[r]);
          lsum += e[r];
        }
        unsigned c[8];
        #pragma unroll
        for (int i = 0; i < 8; ++i) c[i] = cvt_pk_bf16(e[2 * i], e[2 * i + 1]);
        asm volatile("v_permlane32_swap_b32 %0, %1" : "+v"(c[0]), "+v"(c[2]));
        asm volatile("v_permlane32_swap_b32 %0, %1" : "+v"(c[1]), "+v"(c[3]));
        asm volatile("v_permlane32_swap_b32 %0, %1" : "+v"(c[4]), "+v"(c[6]));
        asm volatile("v_permlane32_swap_b32 %0, %1" : "+v"(c[5]), "+v"(c[7]));
        pa[2 * f][0] = c[0]; pa[2 * f][1] = c[1]; pa[2 * f][2] = c[2]; pa[2 * f][3] = c[3];
        pa[2 * f + 1][0] = c[4]; pa[2 * f + 1][1] = c[5];
        pa[2 * f + 1][2] = c[6]; pa[2 * f + 1][3] = c[7];
      }

      // PV: slice m (kv m*16..+16) lives in V half m>>2, sub-slice m&3.
      __builtin_amdgcn_s_setprio(1);
      #pragma unroll
      for (int m = 0; m < 8; ++m) {
        bf16x8 paf = *(const bf16x8*)&pa[m][0];
        const short* Vb = Vs[cur][m >> 2];
        #pragma unroll
        for (int dh = 0; dh < 2; ++dh) {
          int row = dh * 32 + l31;
          bf16x8 vb = *(const bf16x8*)(Vb + row * 64 + (((2 * (m & 3) + hi) ^ (row & 7)) << 3));
          o[dh] = __builtin_amdgcn_mfma_f32_32x32x16_bf16(paf, vb, o[dh], 0, 0, 0);
        }
      }
      __builtin_amdgcn_s_setprio(0);
      __syncthreads();
    }

    lsum += __shfl_xor(lsum, 32);
    #pragma unroll
    for (int r = 0; r < 16; ++r) {
      int crow = (r & 3) + 8 * (r >> 2) + 4 * hi;
      float li = __shfl(lsum, crow, 64);
      float invl = 1.0f / li;
      int s = q0 + crow;
      size_t base = (((size_t)b * SEQ + s) * NH + h) * HD;
      O[base + l31]      = f2bf(o[0][r] * invl);
      O[base + 32 + l31] = f2bf(o[1][r] * invl);
    }
  }
}

extern "C" void kernel_launch(void* const* d_in, const int* in_sizes, int n_in,
                              void* d_out, int out_size, void* d_ws, size_t ws_size,
                              hipStream_t stream) {
  (void)in_sizes; (void)n_in; (void)out_size; (void)ws_size;
  const float* q  = (const float*)d_in[0];
  const float* k  = (const float*)d_in[1];
  const float* v  = (const float*)d_in[2];
  const float* Wq = (const float*)d_in[4];
  const float* bq = (const float*)d_in[5];
  const float* Wk = (const float*)d_in[6];
  const float* bk = (const float*)d_in[7];
  const float* Wv = (const float*)d_in[8];
  const float* bv = (const float*)d_in[9];
  const float* Wo = (const float*)d_in[10];
  const float* bo = (const float*)d_in[11];

  const size_t SQ2 = (size_t)NB * SEQ * NE;        // 8388608
  const size_t W1  = (size_t)NE * NE;              // 4194304
  const size_t W2  = (size_t)(NKV * HD) * NE;      // 1048576
  const size_t KVN = (size_t)NB * NKV * SEQ * HD;  // 2097152

  short* ws = (short*)d_ws;
  short* qb  = ws;
  short* kb  = ws + SQ2;
  short* vb  = ws + 2 * SQ2;
  short* Wqb = ws + 3 * SQ2;
  short* Wkb = Wqb + W1;
  short* Wvb = Wkb + W2;
  short* Wob = Wvb + W2;
  short* Qr  = Wob + W1;
  short* Kr  = Qr + SQ2;
  short* Vr  = Kr + KVN;
  short* Ob  = qb;   // alias: qb dead once attention runs

  dim3 blk(256);

  cvt_all<<<8704, blk, 0, stream>>>(q, qb, k, kb, v, vb, Wq, Wqb, Wk, Wkb, Wv, Wvb, Wo, Wob);
  gemm_qkv256<<<192, dim3(512), 0, stream>>>(qb, Wqb, bq, Qr, kb, Wkb, bk, Kr, vb, Wvb, bv, Vr);
  attn_kernel<<<512, blk, 0, stream>>>(Qr, Kr, Vr, Ob);
  gemm_o<<<512, blk, 0, stream>>>(Ob, Wob, bo, (float*)d_out, NE, NE);
}

// Round 19
// 191.197 us; speedup vs baseline: 1.1547x; 1.1547x over previous
//
#include <hip/hip_runtime.h>
#include <hip/hip_bf16.h>
#include <cmath>

#define NE   2048
#define NH   32
#define NKV  8
#define HD   64
#define SEQ  2048
#define NB   2

typedef __attribute__((ext_vector_type(4))) float f32x4;
typedef __attribute__((ext_vector_type(16))) float f32x16;
typedef __attribute__((ext_vector_type(8))) short bf16x8;
typedef __attribute__((ext_vector_type(4))) short bf16x4;
typedef __attribute__((ext_vector_type(4))) unsigned u32x4;

typedef const __attribute__((address_space(1))) void cgvoid;
typedef __attribute__((address_space(3))) void lvoid;

// SCALE fold: softmax uses exp2; fold (1/8)*log2(e) into Q projection.
#define QSCALE 0.18033688011112042f

__device__ __forceinline__ short f2bf(float f) {
  union { float f; unsigned u; } v; v.f = f;
  unsigned r = v.u + 0x7fffu + ((v.u >> 16) & 1u);
  return (short)(r >> 16);
}

__device__ __forceinline__ unsigned cvt_pk_bf16(float a, float b) {
  unsigned r;
  asm("v_cvt_pk_bf16_f32 %0, %1, %2" : "=v"(r) : "v"(a), "v"(b));
  return r;
}

// ---------------- f32 -> bf16 conversion for the 4 weight tensors ----------------
__global__ __launch_bounds__(256) void cvt_w(
    const float* __restrict__ s0, short* __restrict__ d0,
    const float* __restrict__ s1, short* __restrict__ d1,
    const float* __restrict__ s2, short* __restrict__ d2,
    const float* __restrict__ s3, short* __restrict__ d3)
{
  int idx = blockIdx.x * 256 + threadIdx.x;
  const float* s; short* d; int rel;
  if      (idx < 524288)  { s = s0; d = d0; rel = idx; }
  else if (idx < 655360)  { s = s1; d = d1; rel = idx - 524288; }
  else if (idx < 786432)  { s = s2; d = d2; rel = idx - 655360; }
  else                    { s = s3; d = d3; rel = idx - 786432; }
  size_t off = (size_t)rel * 8;
  f32x4 a = *(const f32x4*)(s + off);
  f32x4 b = *(const f32x4*)(s + off + 4);
  bf16x8 o;
  #pragma unroll
  for (int j = 0; j < 4; ++j) { o[j] = f2bf(a[j]); o[4 + j] = f2bf(b[j]); }
  *(bf16x8*)(d + off) = o;
}

// ================= 256x256 8-wave QKV-projection GEMM, fused f32 A =================
// A read as f32, converted in staging (1-deep regs). LOAD_A(t+1) issued BEFORE
// STAGE_W(t+1) so WRITE_A's compiler wait is vmcnt(4) (W(t+1) survives).
// Block->XCD mapping co-locates all 12 blocks sharing one A-panel on one XCD
// (2 panels x 2MB f32 = 4MB = L2), making A reg-loads L2-hits.
// EPI: 1 = bf16 V^T [b][kv][d][s], 2 = RoPE*QSCALE Q [b][h][s][d],
//      3 = RoPE K [b][kv][s][d]
template<int EPI>
__device__ __forceinline__ void gemm256_body(
    short* As, short* Ws, int m0, int n0,
    const float* __restrict__ A, const short* __restrict__ W,
    const float* __restrict__ bias, void* __restrict__ Cout, int K)
{
  const int t = threadIdx.x, lane = t & 63, w = t >> 6;
  const int lr = lane & 15, lg = lane >> 4;
  const int wm = (w >> 2) * 128, wn = (w & 3) * 64;

  f32x4 acc[8][4];
  #pragma unroll
  for (int i = 0; i < 8; ++i)
    #pragma unroll
    for (int j = 0; j < 4; ++j) acc[i][j] = (f32x4){0.f, 0.f, 0.f, 0.f};

  auto STAGE_W = [&](int kt) {
    const int k0 = kt << 6;
    short* Wd = Ws + (kt & 1) * 16384;
    #pragma unroll
    for (int it = 0; it < 4; ++it) {
      int e = it * 512 + t, r = e >> 3, c = e & 7;
      int cs = ((c ^ (r & 7)) << 3);
      __builtin_amdgcn_global_load_lds((cgvoid*)(W + (size_t)(n0 + r) * K + k0 + cs),
                                       (lvoid*)(Wd + e * 8), 16, 0, 0);
    }
  };

  f32x4 areg[4][2];
  auto LOAD_A = [&](int kt) {
    const int k0 = kt << 6;
    #pragma unroll
    for (int it = 0; it < 4; ++it) {
      int e = it * 512 + t, r = e >> 3, c = e & 7;
      int cs = ((c ^ (r & 7)) << 3);
      const float* src = A + (size_t)(m0 + r) * K + k0 + cs;
      areg[it][0] = *(const f32x4*)(src);
      areg[it][1] = *(const f32x4*)(src + 4);
    }
  };
  auto WRITE_A = [&](int kt) {
    short* Ad = As + (kt & 1) * 16384;
    #pragma unroll
    for (int it = 0; it < 4; ++it) {
      int e = it * 512 + t;
      u32x4 v;
      v[0] = cvt_pk_bf16(areg[it][0][0], areg[it][0][1]);
      v[1] = cvt_pk_bf16(areg[it][0][2], areg[it][0][3]);
      v[2] = cvt_pk_bf16(areg[it][1][0], areg[it][1][1]);
      v[3] = cvt_pk_bf16(areg[it][1][2], areg[it][1][3]);
      *(u32x4*)(Ad + e * 8) = v;
    }
  };

  const int nt = K >> 6;  // 32

  LOAD_A(0);
  STAGE_W(0);
  WRITE_A(0);
  asm volatile("s_waitcnt lgkmcnt(0)" ::: "memory");

  #pragma unroll 1
  for (int ti = 0; ti < nt; ++ti) {
    const short* Ab = As + (ti & 1) * 16384;
    const short* Wb = Ws + (ti & 1) * 16384;
    if (ti + 1 < nt) {
      LOAD_A(ti + 1);
      STAGE_W(ti + 1);
      asm volatile("s_waitcnt vmcnt(12)" ::: "memory");  // drains W(ti)
    } else {
      asm volatile("s_waitcnt vmcnt(0)" ::: "memory");
    }
    __builtin_amdgcn_s_barrier();

    bf16x8 wf[2][4];
    #pragma unroll
    for (int ks = 0; ks < 2; ++ks)
      #pragma unroll
      for (int nf = 0; nf < 4; ++nf) {
        int row = wn + nf * 16 + lr;
        wf[ks][nf] = *(const bf16x8*)(Wb + row * 64 + (((ks * 4 + lg) ^ (row & 7)) << 3));
      }
    #pragma unroll
    for (int mq = 0; mq < 4; ++mq) {
      bf16x8 af[2][2];
      #pragma unroll
      for (int ks = 0; ks < 2; ++ks)
        #pragma unroll
        for (int mi = 0; mi < 2; ++mi) {
          int row = wm + (mq * 2 + mi) * 16 + lr;
          af[ks][mi] = *(const bf16x8*)(Ab + row * 64 + (((ks * 4 + lg) ^ (row & 7)) << 3));
        }
      __builtin_amdgcn_s_setprio(1);
      #pragma unroll
      for (int ks = 0; ks < 2; ++ks)
        #pragma unroll
        for (int mi = 0; mi < 2; ++mi)
          #pragma unroll
          for (int nf = 0; nf < 4; ++nf)
            acc[mq * 2 + mi][nf] =
                __builtin_amdgcn_mfma_f32_16x16x32_bf16(af[ks][mi], wf[ks][nf],
                                                        acc[mq * 2 + mi][nf], 0, 0, 0);
      __builtin_amdgcn_s_setprio(0);
    }
    if (ti + 1 < nt) WRITE_A(ti + 1);   // waits vmcnt(4): W(ti+1) stays in flight
    asm volatile("s_waitcnt lgkmcnt(0)" ::: "memory");
    __builtin_amdgcn_s_barrier();
  }

  if (EPI == 1) {
    short* C = (short*)Cout;
    #pragma unroll
    for (int mf = 0; mf < 8; ++mf)
      #pragma unroll
      for (int nf = 0; nf < 4; ++nf) {
        int n = n0 + wn + nf * 16 + lr;
        int kv = n >> 6, d = n & 63;
        int mb = m0 + wm + mf * 16 + lg * 4;
        int b = mb >> 11, s = mb & (SEQ - 1);
        bf16x4 pb;
        #pragma unroll
        for (int i = 0; i < 4; ++i) pb[i] = f2bf(acc[mf][nf][i] + bias[n]);
        *(bf16x4*)(C + (((size_t)b * NKV + kv) * HD + d) * SEQ + s) = pb;
      }
  } else {
    const int HN = (EPI == 2) ? NH : NKV;
    short* C = (short*)Cout;
    #pragma unroll
    for (int mf = 0; mf < 8; ++mf)
      #pragma unroll
      for (int nf2 = 0; nf2 < 2; ++nf2) {
        int n1 = n0 + wn + nf2 * 16 + lr;
        int d1 = n1 & 63;  // < 32
        int h = n1 >> 6;
        float inv = exp2f(-(float)d1 * (13.287712379549449f / 32.0f));
        #pragma unroll
        for (int i = 0; i < 4; ++i) {
          int m = m0 + wm + mf * 16 + lg * 4 + i;
          int b = m >> 11, s = m & (SEQ - 1);
          float v1 = acc[mf][nf2][i] + bias[n1];
          float v2 = acc[mf][nf2 + 2][i] + bias[n1 + 32];
          float ang = (float)s * inv;
          float c, sn;
          __sincosf(ang, &sn, &c);
          float o1 = v1 * c - v2 * sn;
          float o2 = v2 * c + v1 * sn;
          if (EPI == 2) { o1 *= QSCALE; o2 *= QSCALE; }
          size_t base = (((size_t)b * HN + h) * SEQ + s) * HD;
          C[base + d1]      = f2bf(o1);
          C[base + d1 + 32] = f2bf(o2);
        }
      }
  }
}

// Block->XCD mapping: all 12 blocks sharing one A-panel (same m-index mm:
// 8 Q-N-tiles + 2 K + 2 V) land on XCD (mm&7). Bijective onto bid 0..191.
__global__ __launch_bounds__(512, 2) void gemm_qkv256(
    const float* __restrict__ qA, const short* __restrict__ Wq,
    const float* __restrict__ bq, short* __restrict__ Qout,
    const float* __restrict__ kA, const short* __restrict__ Wk,
    const float* __restrict__ bk, short* __restrict__ Kout,
    const float* __restrict__ vA, const short* __restrict__ Wv,
    const float* __restrict__ bv, short* __restrict__ Vout)
{
  __shared__ __align__(16) short As[2 * 256 * 64];
  __shared__ __align__(16) short Ws[2 * 256 * 64];
  int orig = blockIdx.x;
  int xcd = orig & 7, idx = orig >> 3;           // idx 0..23
  int hiP = (idx >= 12) ? 1 : 0;
  int mm = xcd + 8 * hiP;                        // A-panel index 0..15
  int j = idx - 12 * hiP;                        // 0..11
  if (j < 8) {
    gemm256_body<2>(As, Ws, mm * 256, j * 256, qA, Wq, bq, (void*)Qout, NE);
  } else if (j < 10) {
    gemm256_body<3>(As, Ws, mm * 256, (j - 8) * 256, kA, Wk, bk, (void*)Kout, NE);
  } else {
    gemm256_body<1>(As, Ws, mm * 256, (j - 10) * 256, vA, Wv, bv, (void*)Vout, NE);
  }
}

// ================= O-projection: 128x128 BK=64 dbuf, phase-pinned (R11) =========
__global__ __launch_bounds__(256) void gemm_o(
    const short* __restrict__ A, const short* __restrict__ W,
    const float* __restrict__ bias, float* __restrict__ C, int N, int K)
{
  __shared__ __align__(16) short As[2 * 128 * 64];
  __shared__ __align__(16) short Ws[2 * 128 * 64];
  const int t = threadIdx.x, lane = t & 63, w = t >> 6;
  const int lr = lane & 15, lg = lane >> 4;
  const int wm = (w >> 1) * 64, wn = (w & 1) * 64;
  const int L = blockIdx.x;
  const int xcd = L & 7, slot = L >> 3;
  const int bx = xcd + 8 * (slot >> 4);
  const int byy = slot & 15;
  const int m0 = bx * 128, n0 = byy * 128;

  f32x4 acc[4][4];
  #pragma unroll
  for (int i = 0; i < 4; ++i)
    #pragma unroll
    for (int j = 0; j < 4; ++j) acc[i][j] = (f32x4){0.f, 0.f, 0.f, 0.f};

  const int nt = K >> 6;
  #pragma unroll
  for (int it = 0; it < 4; ++it) {
    int e = it * 256 + t, r = e >> 3, c = e & 7;
    int cs = ((c ^ (r & 7)) << 3);
    __builtin_amdgcn_global_load_lds((cgvoid*)(A + (size_t)(m0 + r) * K + cs),
                                     (lvoid*)(As + e * 8), 16, 0, 0);
    __builtin_amdgcn_global_load_lds((cgvoid*)(W + (size_t)(n0 + r) * K + cs),
                                     (lvoid*)(Ws + e * 8), 16, 0, 0);
  }

  for (int ti = 0; ti < nt; ++ti) {
    const int cur = ti & 1;
    const short* Ab = As + cur * 8192;
    const short* Wb = Ws + cur * 8192;
    if (ti + 1 < nt) {
      const int k0 = (ti + 1) << 6;
      short* An = As + (cur ^ 1) * 8192;
      short* Wn = Ws + (cur ^ 1) * 8192;
      #pragma unroll
      for (int it = 0; it < 4; ++it) {
        int e = it * 256 + t, r = e >> 3, c = e & 7;
        int cs = ((c ^ (r & 7)) << 3);
        __builtin_amdgcn_global_load_lds((cgvoid*)(A + (size_t)(m0 + r) * K + k0 + cs),
                                         (lvoid*)(An + e * 8), 16, 0, 0);
        __builtin_amdgcn_global_load_lds((cgvoid*)(W + (size_t)(n0 + r) * K + k0 + cs),
                                         (lvoid*)(Wn + e * 8), 16, 0, 0);
      }
      asm volatile("s_waitcnt vmcnt(8)" ::: "memory");
    } else {
      asm volatile("s_waitcnt vmcnt(0)" ::: "memory");
    }
    __builtin_amdgcn_s_barrier();
    __builtin_amdgcn_sched_barrier(0);

    bf16x8 wf[2][4];
    #pragma unroll
    for (int ks = 0; ks < 2; ++ks)
      #pragma unroll
      for (int nf = 0; nf < 4; ++nf) {
        int row = wn + nf * 16 + lr;
        wf[ks][nf] = *(const bf16x8*)(Wb + row * 64 + (((ks * 4 + lg) ^ (row & 7)) << 3));
      }
    #pragma unroll
    for (int mq = 0; mq < 2; ++mq) {
      bf16x8 af[2][2];
      #pragma unroll
      for (int ks = 0; ks < 2; ++ks)
        #pragma unroll
        for (int mi = 0; mi < 2; ++mi) {
          int row = wm + (mq * 2 + mi) * 16 + lr;
          af[ks][mi] = *(const bf16x8*)(Ab + row * 64 + (((ks * 4 + lg) ^ (row & 7)) << 3));
        }
      __builtin_amdgcn_s_setprio(1);
      #pragma unroll
      for (int ks = 0; ks < 2; ++ks)
        #pragma unroll
        for (int mi = 0; mi < 2; ++mi)
          #pragma unroll
          for (int nf = 0; nf < 4; ++nf)
            acc[mq * 2 + mi][nf] =
                __builtin_amdgcn_mfma_f32_16x16x32_bf16(af[ks][mi], wf[ks][nf],
                                                        acc[mq * 2 + mi][nf], 0, 0, 0);
      __builtin_amdgcn_s_setprio(0);
      __builtin_amdgcn_s_barrier();
      __builtin_amdgcn_sched_barrier(0);
    }
  }

  #pragma unroll
  for (int mf = 0; mf < 4; ++mf)
    #pragma unroll
    for (int nf = 0; nf < 4; ++nf)
      #pragma unroll
      for (int i = 0; i < 4; ++i) {
        int m = m0 + wm + mf * 16 + lg * 4 + i;
        int n = n0 + wn + nf * 16 + lr;
        C[(size_t)m * N + n] = acc[mf][nf][i] + bias[n];
      }
}

// ---------------- Flash attention, causal, GQA-shared KV, 32x32 MFMA, KVBLK=64 ----
__global__ __launch_bounds__(256) void attn_kernel(
    const short* __restrict__ Q, const short* __restrict__ K,
    const short* __restrict__ Vt, short* __restrict__ O)
{
  __shared__ __align__(16) short Ks[2][64 * 64];
  __shared__ __align__(16) short Vs[2][64 * 64];

  const int t = threadIdx.x, lane = t & 63, w = t >> 6;
  const int l31 = lane & 31, hi = lane >> 5;
  const int L = blockIdx.x;
  const int xcd = L & 7, slot = L >> 3;
  const int by = xcd + 8 * (slot >> 5);
  const int bx = slot & 31;
  const int b = by >> 3, kvh = by & 7;
  const int h = kvh * 4 + w;

  const short* Qh = Q + ((size_t)b * NH + h) * SEQ * HD;
  const short* Kh = K + ((size_t)b * NKV + kvh) * SEQ * HD;
  const short* Vh = Vt + ((size_t)b * NKV + kvh) * (size_t)HD * SEQ;

  #pragma unroll 1
  for (int pass = 0; pass < 2; ++pass) {
    const int qb32 = pass ? bx : (63 - bx);
    const int q0 = qb32 * 32;
    const int ntile = (qb32 >> 1) + 1;
    const int qpos = q0 + l31;

    bf16x8 qfr[4];
    #pragma unroll
    for (int dd = 0; dd < 4; ++dd)
      qfr[dd] = *(const bf16x8*)(Qh + (size_t)(q0 + l31) * HD + dd * 16 + hi * 8);

    f32x16 o[2];
    #pragma unroll
    for (int dh = 0; dh < 2; ++dh)
      #pragma unroll
      for (int r = 0; r < 16; ++r) o[dh][r] = 0.f;
    float lsum = 0.f;

    #pragma unroll
    for (int it = 0; it < 2; ++it) {
      int cid = it * 256 + t;
      int r = cid >> 3, c = cid & 7;
      int cs = ((c ^ (r & 7)) << 3);
      __builtin_amdgcn_global_load_lds((cgvoid*)(Kh + (size_t)r * HD + cs),
                                       (lvoid*)(Ks[0] + cid * 8), 16, 0, 0);
      __builtin_amdgcn_global_load_lds((cgvoid*)(Vh + (size_t)r * SEQ + cs),
                                       (lvoid*)(Vs[0] + cid * 8), 16, 0, 0);
    }
    __syncthreads();

    for (int ti = 0; ti < ntile; ++ti) {
      const int cur = ti & 1;
      if (ti + 1 < ntile) {
        const int kvn = (ti + 1) * 64;
        #pragma unroll
        for (int it = 0; it < 2; ++it) {
          int cid = it * 256 + t;
          int r = cid >> 3, c = cid & 7;
          int cs = ((c ^ (r & 7)) << 3);
          __builtin_amdgcn_global_load_lds((cgvoid*)(Kh + (size_t)(kvn + r) * HD + cs),
                                           (lvoid*)(Ks[cur ^ 1] + cid * 8), 16, 0, 0);
          __builtin_amdgcn_global_load_lds((cgvoid*)(Vh + (size_t)r * SEQ + kvn + cs),
                                           (lvoid*)(Vs[cur ^ 1] + cid * 8), 16, 0, 0);
        }
      }
      const int kv0 = ti * 64;
      const short* Kb = Ks[cur];
      const short* Vb = Vs[cur];

      f32x16 p[2];
      __builtin_amdgcn_s_setprio(1);
      #pragma unroll
      for (int f = 0; f < 2; ++f) {
        f32x16 z;
        #pragma unroll
        for (int r = 0; r < 16; ++r) z[r] = 0.f;
        #pragma unroll
        for (int dd = 0; dd < 4; ++dd) {
          int row = f * 32 + l31;
          bf16x8 ka = *(const bf16x8*)(Kb + row * 64 + (((2 * dd + hi) ^ (row & 7)) << 3));
          z = __builtin_amdgcn_mfma_f32_32x32x16_bf16(ka, qfr[dd], z, 0, 0, 0);
        }
        p[f] = z;
      }
      __builtin_amdgcn_s_setprio(0);

      if (ti == ntile - 1) {
        #pragma unroll
        for (int f = 0; f < 2; ++f)
          #pragma unroll
          for (int r = 0; r < 16; ++r) {
            int kpos = kv0 + f * 32 + (r & 3) + 8 * (r >> 2) + 4 * hi;
            if (kpos > qpos) p[f][r] = -INFINITY;
          }
      }

      unsigned pa[4][4];
      #pragma unroll
      for (int f = 0; f < 2; ++f) {
        float e[16];
        #pragma unroll
        for (int r = 0; r < 16; ++r) {
          e[r] = __builtin_amdgcn_exp2f(p[f][r]);
          lsum += e[r];
        }
        unsigned c[8];
        #pragma unroll
        for (int i = 0; i < 8; ++i) c[i] = cvt_pk_bf16(e[2 * i], e[2 * i + 1]);
        asm volatile("v_permlane32_swap_b32 %0, %1" : "+v"(c[0]), "+v"(c[2]));
        asm volatile("v_permlane32_swap_b32 %0, %1" : "+v"(c[1]), "+v"(c[3]));
        asm volatile("v_permlane32_swap_b32 %0, %1" : "+v"(c[4]), "+v"(c[6]));
        asm volatile("v_permlane32_swap_b32 %0, %1" : "+v"(c[5]), "+v"(c[7]));
        pa[2 * f][0] = c[0]; pa[2 * f][1] = c[1]; pa[2 * f][2] = c[2]; pa[2 * f][3] = c[3];
        pa[2 * f + 1][0] = c[4]; pa[2 * f + 1][1] = c[5];
        pa[2 * f + 1][2] = c[6]; pa[2 * f + 1][3] = c[7];
      }

      __builtin_amdgcn_s_setprio(1);
      #pragma unroll
      for (int ks = 0; ks < 4; ++ks) {
        bf16x8 paf = *(const bf16x8*)&pa[ks][0];
        #pragma unroll
        for (int dh = 0; dh < 2; ++dh) {
          int row = dh * 32 + l31;
          bf16x8 vb = *(const bf16x8*)(Vb + row * 64 + (((2 * ks + hi) ^ (row & 7)) << 3));
          o[dh] = __builtin_amdgcn_mfma_f32_32x32x16_bf16(paf, vb, o[dh], 0, 0, 0);
        }
      }
      __builtin_amdgcn_s_setprio(0);
      __syncthreads();
    }

    lsum += __shfl_xor(lsum, 32);
    #pragma unroll
    for (int r = 0; r < 16; ++r) {
      int crow = (r & 3) + 8 * (r >> 2) + 4 * hi;
      float li = __shfl(lsum, crow, 64);
      float invl = 1.0f / li;
      int s = q0 + crow;
      size_t base = (((size_t)b * SEQ + s) * NH + h) * HD;
      O[base + l31]      = f2bf(o[0][r] * invl);
      O[base + 32 + l31] = f2bf(o[1][r] * invl);
    }
  }
}

extern "C" void kernel_launch(void* const* d_in, const int* in_sizes, int n_in,
                              void* d_out, int out_size, void* d_ws, size_t ws_size,
                              hipStream_t stream) {
  (void)in_sizes; (void)n_in; (void)out_size; (void)ws_size;
  const float* q  = (const float*)d_in[0];
  const float* k  = (const float*)d_in[1];
  const float* v  = (const float*)d_in[2];
  const float* Wq = (const float*)d_in[4];
  const float* bq = (const float*)d_in[5];
  const float* Wk = (const float*)d_in[6];
  const float* bk = (const float*)d_in[7];
  const float* Wv = (const float*)d_in[8];
  const float* bv = (const float*)d_in[9];
  const float* Wo = (const float*)d_in[10];
  const float* bo = (const float*)d_in[11];

  const size_t SQ2 = (size_t)NB * SEQ * NE;        // 8388608
  const size_t W1  = (size_t)NE * NE;              // 4194304
  const size_t W2  = (size_t)(NKV * HD) * NE;      // 1048576
  const size_t KVN = (size_t)NB * NKV * SEQ * HD;  // 2097152

  short* ws = (short*)d_ws;
  short* Wqb = ws;
  short* Wkb = Wqb + W1;
  short* Wvb = Wkb + W2;
  short* Wob = Wvb + W2;
  short* Qr  = Wob + W1;
  short* Kr  = Qr + SQ2;
  short* Vr  = Kr + KVN;
  short* Ob  = Vr + KVN;

  dim3 blk(256);

  cvt_w<<<5120, blk, 0, stream>>>(Wq, Wqb, Wk, Wkb, Wv, Wvb, Wo, Wob);
  gemm_qkv256<<<192, dim3(512), 0, stream>>>(q, Wqb, bq, Qr, k, Wkb, bk, Kr, v, Wvb, bv, Vr);
  attn_kernel<<<512, blk, 0, stream>>>(Qr, Kr, Vr, Ob);
  gemm_o<<<512, blk, 0, stream>>>(Ob, Wob, bo, (float*)d_out, NE, NE);
}